// Round 11
// baseline (443.699 us; speedup 1.0000x reference)
//
#include <hip/hip_runtime.h>
#include <hip/hip_bf16.h>
#include <math.h>

#define NN_DIN 512
#define NN_HF  256
#define NN_H   8
#define NN_F   32
#define NN_C   40

typedef short bf16x8 __attribute__((ext_vector_type(8)));
typedef float f32x4 __attribute__((ext_vector_type(4)));

__device__ __forceinline__ unsigned short f2bf_rne(float x) {
    unsigned u = __builtin_bit_cast(unsigned, x);
    unsigned r = u + 0x7FFFu + ((u >> 16) & 1u);
    return (unsigned short)(r >> 16);
}
__device__ __forceinline__ float bfu2f(unsigned short s) {
    unsigned u = ((unsigned)s) << 16;
    return __builtin_bit_cast(float, u);
}

// ---------------- W1 transpose + RNE bf16: [512][256] f32 -> [256][512] bf16 ----
__global__ __launch_bounds__(256) void w1rne_kernel(
    const float* __restrict__ W1, unsigned short* __restrict__ Wh)
{
    __shared__ float tile[32][33];
    int bk = blockIdx.x * 32;
    int bn = blockIdx.y * 32;
    int tx = threadIdx.x & 31, ty = threadIdx.x >> 5;   // ty 0..7
    #pragma unroll
    for (int i = 0; i < 32; i += 8)
        tile[ty + i][tx] = W1[(size_t)(bk + ty + i) * NN_HF + bn + tx];
    __syncthreads();
    #pragma unroll
    for (int i = 0; i < 32; i += 8) {
        float v = tile[tx][ty + i];
        Wh[(size_t)(bn + ty + i) * NN_DIN + bk + tx] = f2bf_rne(v);
    }
}

// ---------------- W2 transpose + RNE bf16: [256][40] f32 -> [48][256] bf16 (pad 0) ----
__global__ __launch_bounds__(256) void w2rne_kernel(
    const float* __restrict__ W2, unsigned short* __restrict__ W2T)
{
    int idx = blockIdx.x * 256 + threadIdx.x;    // 48*256 = 12288
    if (idx >= 48 * 256) return;
    int c = idx >> 8;       // output col (row of W2T), 0..47
    int k = idx & 255;
    unsigned short v = 0;
    if (c < NN_C) v = f2bf_rne(W2[(size_t)k * NN_C + c]);
    W2T[idx] = v;
}

// ---------------- GEMM1 (MFMA, x read once) + fused a1s/a1d epilogue ----------
#define G1_BM 64
#define G1_BN 256
#define G1_BK 64
#define G1_LDK 72

__global__ __launch_bounds__(256) void gemm1_kernel(
    const float* __restrict__ A, const unsigned short* __restrict__ BT,
    const float* __restrict__ as1, const float* __restrict__ ad1,
    unsigned short* __restrict__ Cb, float* __restrict__ a1s,
    float* __restrict__ a1d, int M)
{
    __shared__ unsigned short Ah[G1_BM][G1_LDK];
    __shared__ unsigned short Bh[G1_BN][G1_LDK];
    const int m0 = blockIdx.x * G1_BM;
    const int tid = threadIdx.x;
    const int wave = tid >> 6, lane = tid & 63;
    const int wn = wave;
    const int lr = lane & 15, lg = lane >> 4;

    const int amr[4] = { (tid + 0*256) >> 4, (tid + 1*256) >> 4,
                         (tid + 2*256) >> 4, (tid + 3*256) >> 4 };
    const int akc = (tid & 15) << 2;
    const int bnr[8] = { (tid + 0*256) >> 3, (tid + 1*256) >> 3,
                         (tid + 2*256) >> 3, (tid + 3*256) >> 3,
                         (tid + 4*256) >> 3, (tid + 5*256) >> 3,
                         (tid + 6*256) >> 3, (tid + 7*256) >> 3 };
    const int bkc = (tid & 7) << 3;

    f32x4 acc[4][4];
    #pragma unroll
    for (int i = 0; i < 4; ++i)
        #pragma unroll
        for (int j = 0; j < 4; ++j) acc[i][j] = (f32x4){0.f, 0.f, 0.f, 0.f};

    float4 ra[4];
    bf16x8 rb[8];

    #pragma unroll
    for (int i = 0; i < 4; ++i) {
        ra[i] = make_float4(0.f, 0.f, 0.f, 0.f);
        if (m0 + amr[i] < M)
            ra[i] = *(const float4*)(A + (size_t)(m0 + amr[i]) * NN_DIN + akc);
    }
    #pragma unroll
    for (int i = 0; i < 8; ++i)
        rb[i] = *(const bf16x8*)(BT + (size_t)bnr[i] * NN_DIN + bkc);
    #pragma unroll
    for (int i = 0; i < 4; ++i) {
        ushort4 hv;
        hv.x = f2bf_rne(ra[i].x); hv.y = f2bf_rne(ra[i].y);
        hv.z = f2bf_rne(ra[i].z); hv.w = f2bf_rne(ra[i].w);
        *reinterpret_cast<ushort4*>(&Ah[amr[i]][akc]) = hv;
    }
    #pragma unroll
    for (int i = 0; i < 8; ++i)
        *reinterpret_cast<bf16x8*>(&Bh[bnr[i]][bkc]) = rb[i];
    __syncthreads();

    const int NSTEP = NN_DIN / G1_BK;   // 8
    for (int step = 0; step < NSTEP; ++step) {
        const bool last = (step == NSTEP - 1);
        if (!last) {
            int k0 = (step + 1) * G1_BK;
            #pragma unroll
            for (int i = 0; i < 4; ++i) {
                ra[i] = make_float4(0.f, 0.f, 0.f, 0.f);
                if (m0 + amr[i] < M)
                    ra[i] = *(const float4*)(A + (size_t)(m0 + amr[i]) * NN_DIN + k0 + akc);
            }
            #pragma unroll
            for (int i = 0; i < 8; ++i)
                rb[i] = *(const bf16x8*)(BT + (size_t)bnr[i] * NN_DIN + k0 + bkc);
        }
        #pragma unroll
        for (int ks = 0; ks < 2; ++ks) {
            const int kb = (ks << 5) + (lg << 3);
            bf16x8 fah[4], fbh[4];
            #pragma unroll
            for (int mi = 0; mi < 4; ++mi) {
                int m = (mi << 4) + lr;
                fah[mi] = *reinterpret_cast<const bf16x8*>(&Ah[m][kb]);
            }
            #pragma unroll
            for (int ni = 0; ni < 4; ++ni) {
                int n = (wn << 6) + (ni << 4) + lr;
                fbh[ni] = *reinterpret_cast<const bf16x8*>(&Bh[n][kb]);
            }
            #pragma unroll
            for (int mi = 0; mi < 4; ++mi)
                #pragma unroll
                for (int ni = 0; ni < 4; ++ni)
                    acc[mi][ni] = __builtin_amdgcn_mfma_f32_16x16x32_bf16(
                        fah[mi], fbh[ni], acc[mi][ni], 0, 0, 0);
        }
        __syncthreads();
        if (!last) {
            #pragma unroll
            for (int i = 0; i < 4; ++i) {
                ushort4 hv;
                hv.x = f2bf_rne(ra[i].x); hv.y = f2bf_rne(ra[i].y);
                hv.z = f2bf_rne(ra[i].z); hv.w = f2bf_rne(ra[i].w);
                *reinterpret_cast<ushort4*>(&Ah[amr[i]][akc]) = hv;
            }
            #pragma unroll
            for (int i = 0; i < 8; ++i)
                *reinterpret_cast<bf16x8*>(&Bh[bnr[i]][bkc]) = rb[i];
            __syncthreads();
        }
    }
    // epilogue: C write + fused attention-coefficient reduction.
    float asv[4], adv[4];
    #pragma unroll
    for (int ni = 0; ni < 4; ++ni) {
        int c = (wn << 6) + (ni << 4) + lr;
        asv[ni] = as1[c]; adv[ni] = ad1[c];
    }
    #pragma unroll
    for (int mi = 0; mi < 4; ++mi)
        #pragma unroll
        for (int r = 0; r < 4; ++r) {
            int row = m0 + (mi << 4) + (lg << 2) + r;
            float v0 = acc[mi][0][r], v1 = acc[mi][1][r];
            float v2 = acc[mi][2][r], v3 = acc[mi][3][r];
            if (row < M) {
                Cb[(size_t)row * NN_HF + (wn << 6) + (0 << 4) + lr] = f2bf_rne(v0);
                Cb[(size_t)row * NN_HF + (wn << 6) + (1 << 4) + lr] = f2bf_rne(v1);
                Cb[(size_t)row * NN_HF + (wn << 6) + (2 << 4) + lr] = f2bf_rne(v2);
                Cb[(size_t)row * NN_HF + (wn << 6) + (3 << 4) + lr] = f2bf_rne(v3);
            }
            float ps0 = v0 * asv[0] + v1 * asv[1];
            float pd0 = v0 * adv[0] + v1 * adv[1];
            float ps1 = v2 * asv[2] + v3 * asv[3];
            float pd1 = v2 * adv[2] + v3 * adv[3];
            #pragma unroll
            for (int off = 1; off < 16; off <<= 1) {
                ps0 += __shfl_xor(ps0, off); pd0 += __shfl_xor(pd0, off);
                ps1 += __shfl_xor(ps1, off); pd1 += __shfl_xor(pd1, off);
            }
            if (lr == 0 && row < M) {
                a1s[row * NN_H + 2 * wn]     = ps0;
                a1s[row * NN_H + 2 * wn + 1] = ps1;
                a1d[row * NN_H + 2 * wn]     = pd0;
                a1d[row * NN_H + 2 * wn + 1] = pd1;
            }
        }
}

// ---------------- CSR build ----------------
__global__ void count_kernel(const int* __restrict__ dst, int* __restrict__ deg,
                             int E, int Nn)
{
    int e = blockIdx.x * blockDim.x + threadIdx.x;
    int Et = E + Nn;
    if (e >= Et) return;
    int d = (e < E) ? dst[e] : (e - E);     // self-loops appended
    atomicAdd(&deg[d], 1);
}

#define SCAN_CHUNK 1024
__global__ __launch_bounds__(256) void scan1_kernel(
    const int* __restrict__ deg, int* __restrict__ offs,
    int* __restrict__ bsums, int Nn)
{
    __shared__ int sh[256];
    int b = blockIdx.x, t = threadIdx.x;
    int base = b * SCAN_CHUNK + t * 4;
    int v[4];
    int tot = 0;
    #pragma unroll
    for (int i = 0; i < 4; ++i) {
        v[i] = (base + i < Nn) ? deg[base + i] : 0;
        tot += v[i];
    }
    sh[t] = tot;
    __syncthreads();
    for (int off = 1; off < 256; off <<= 1) {
        int y = (t >= off) ? sh[t - off] : 0;
        __syncthreads();
        sh[t] += y;
        __syncthreads();
    }
    int p = sh[t] - tot;
    #pragma unroll
    for (int i = 0; i < 4; ++i) {
        if (base + i < Nn) offs[base + i] = p;
        p += v[i];
    }
    if (t == 255) bsums[b] = sh[255];
}

__global__ void scan2_kernel(int* __restrict__ bsums, int nb)
{
    if (threadIdx.x == 0) {
        int run = 0;
        for (int i = 0; i < nb; ++i) {
            int tmp = bsums[i];
            bsums[i] = run;
            run += tmp;
        }
    }
}

__global__ void scan3_kernel(int* __restrict__ offs, const int* __restrict__ bsums,
                             int Nn, int Et)
{
    int i = blockIdx.x * blockDim.x + threadIdx.x;
    if (i < Nn) offs[i] += bsums[i >> 10];
    if (i == 0) offs[Nn] = Et;
}

__global__ void fill_kernel(const int* __restrict__ src, const int* __restrict__ dst,
                            const int* __restrict__ offs, int* __restrict__ cursor,
                            int* __restrict__ srcs, int E, int Nn)
{
    int e = blockIdx.x * blockDim.x + threadIdx.x;
    int Et = E + Nn;
    if (e >= Et) return;
    int d, s;
    if (e < E) { d = dst[e]; s = src[e]; }
    else       { d = e - E;  s = e - E;  }
    int pos = offs[d] + atomicAdd(&cursor[d], 1);
    srcs[pos] = s;
}

// ---------------- layer-1 FUSED softmax+aggregate (max-free, 8-edge MLP) ------
__global__ __launch_bounds__(256) void agg1_kernel(
    const unsigned short* __restrict__ h1b, const float* __restrict__ a1s,
    const float* __restrict__ a1d, const int* __restrict__ offs,
    const int* __restrict__ srcs, const float* __restrict__ b1,
    unsigned short* __restrict__ hp1b, int Nn)
{
    int n = blockIdx.x * 4 + (threadIdx.x >> 6);
    if (n >= Nn) return;
    int lane = threadIdx.x & 63;
    int beg = offs[n], end = offs[n + 1];

    // ---- pass 1: max-free exp-sum per head ----
    int g = lane >> 3, hh = lane & 7;
    float adn1 = a1d[n * NN_H + hh];
    float s = 0.f;
    for (int k = beg + g; k < end; k += 8) {
        float e = a1s[srcs[k] * NN_H + hh] + adn1;
        e = e > 0.f ? e : 0.2f * e;
        s += __expf(e);
    }
    #pragma unroll
    for (int off = 8; off < 64; off <<= 1) s += __shfl_xor(s, off);
    float inv = 1.f / (s + 1e-16f);

    // ---- pass 2 layout: half-wave per edge, lane covers 8 features ----
    int hl = lane & 31;
    int h = hl >> 2;
    int half = lane >> 5;
    float invh = __shfl(inv, h);
    float adn  = __shfl(adn1, h);

    float c0[8] = {0,0,0,0,0,0,0,0};
    float c1[8] = {0,0,0,0,0,0,0,0};
    float c2[8] = {0,0,0,0,0,0,0,0};
    float c3[8] = {0,0,0,0,0,0,0,0};
    int k = beg;
    for (; k + 7 < end; k += 8) {
        int s0 = srcs[k + half];
        int s1 = srcs[k + 2 + half];
        int s2 = srcs[k + 4 + half];
        int s3 = srcs[k + 6 + half];
        float e0 = a1s[s0 * NN_H + h] + adn;
        float e1 = a1s[s1 * NN_H + h] + adn;
        float e2 = a1s[s2 * NN_H + h] + adn;
        float e3 = a1s[s3 * NN_H + h] + adn;
        e0 = e0 > 0.f ? e0 : 0.2f * e0;  e1 = e1 > 0.f ? e1 : 0.2f * e1;
        e2 = e2 > 0.f ? e2 : 0.2f * e2;  e3 = e3 > 0.f ? e3 : 0.2f * e3;
        float w0 = __expf(e0) * invh;
        float w1 = __expf(e1) * invh;
        float w2 = __expf(e2) * invh;
        float w3 = __expf(e3) * invh;
        bf16x8 v0 = *(const bf16x8*)(h1b + (size_t)s0 * NN_HF + hl * 8);
        bf16x8 v1 = *(const bf16x8*)(h1b + (size_t)s1 * NN_HF + hl * 8);
        bf16x8 v2 = *(const bf16x8*)(h1b + (size_t)s2 * NN_HF + hl * 8);
        bf16x8 v3 = *(const bf16x8*)(h1b + (size_t)s3 * NN_HF + hl * 8);
        #pragma unroll
        for (int j = 0; j < 8; ++j) {
            c0[j] = fmaf(w0, bfu2f((unsigned short)v0[j]), c0[j]);
            c1[j] = fmaf(w1, bfu2f((unsigned short)v1[j]), c1[j]);
            c2[j] = fmaf(w2, bfu2f((unsigned short)v2[j]), c2[j]);
            c3[j] = fmaf(w3, bfu2f((unsigned short)v3[j]), c3[j]);
        }
    }
    for (; k + 3 < end; k += 4) {
        int s0 = srcs[k + half];
        int s1 = srcs[k + 2 + half];
        float e0 = a1s[s0 * NN_H + h] + adn;
        float e1 = a1s[s1 * NN_H + h] + adn;
        e0 = e0 > 0.f ? e0 : 0.2f * e0;
        e1 = e1 > 0.f ? e1 : 0.2f * e1;
        float w0 = __expf(e0) * invh;
        float w1 = __expf(e1) * invh;
        bf16x8 v0 = *(const bf16x8*)(h1b + (size_t)s0 * NN_HF + hl * 8);
        bf16x8 v1 = *(const bf16x8*)(h1b + (size_t)s1 * NN_HF + hl * 8);
        #pragma unroll
        for (int j = 0; j < 8; ++j) {
            c0[j] = fmaf(w0, bfu2f((unsigned short)v0[j]), c0[j]);
            c1[j] = fmaf(w1, bfu2f((unsigned short)v1[j]), c1[j]);
        }
    }
    for (; k + 1 < end; k += 2) {
        int s0 = srcs[k + half];
        float e0 = a1s[s0 * NN_H + h] + adn;
        e0 = e0 > 0.f ? e0 : 0.2f * e0;
        float w0 = __expf(e0) * invh;
        bf16x8 v0 = *(const bf16x8*)(h1b + (size_t)s0 * NN_HF + hl * 8);
        #pragma unroll
        for (int j = 0; j < 8; ++j)
            c0[j] = fmaf(w0, bfu2f((unsigned short)v0[j]), c0[j]);
    }
    if (k < end) {
        int s0 = srcs[k];
        float e0 = a1s[s0 * NN_H + h] + adn;
        e0 = e0 > 0.f ? e0 : 0.2f * e0;
        float w0 = (half == 0) ? __expf(e0) * invh : 0.f;
        bf16x8 v0 = *(const bf16x8*)(h1b + (size_t)s0 * NN_HF + hl * 8);
        #pragma unroll
        for (int j = 0; j < 8; ++j)
            c0[j] = fmaf(w0, bfu2f((unsigned short)v0[j]), c0[j]);
    }
    #pragma unroll
    for (int j = 0; j < 8; ++j) {
        c0[j] = (c0[j] + c1[j]) + (c2[j] + c3[j]);
        c0[j] += __shfl_xor(c0[j], 32);
    }
    if (half == 0) {
        float4 bb0 = *(const float4*)(b1 + hl * 8);
        float4 bb1 = *(const float4*)(b1 + hl * 8 + 4);
        float r[8];
        r[0] = c0[0] + bb0.x; r[1] = c0[1] + bb0.y;
        r[2] = c0[2] + bb0.z; r[3] = c0[3] + bb0.w;
        r[4] = c0[4] + bb1.x; r[5] = c0[5] + bb1.y;
        r[6] = c0[6] + bb1.z; r[7] = c0[7] + bb1.w;
        bf16x8 ov;
        #pragma unroll
        for (int j = 0; j < 8; ++j) {
            float v = r[j] > 0.f ? r[j] : __expf(r[j]) - 1.f;   // ELU
            ov[j] = (short)f2bf_rne(v);
        }
        *(bf16x8*)(hp1b + (size_t)n * NN_HF + hl * 8) = ov;
    }
}

// ---------------- GEMM2 (MFMA): h2b = bf16(hp1b @ W2), fused a2s/a2d ----------
#define G2_BM 128

__global__ __launch_bounds__(256) void gemm2_kernel(
    const unsigned short* __restrict__ Ab, const unsigned short* __restrict__ W2T,
    const float* __restrict__ att_s, const float* __restrict__ att_d,
    unsigned short* __restrict__ h2b, float* __restrict__ a2s,
    float* __restrict__ a2d, int M)
{
    __shared__ unsigned short Ah[G2_BM][72];
    __shared__ unsigned short Bh[48][72];
    const int m0 = blockIdx.x * G2_BM;
    const int tid = threadIdx.x;
    const int wave = tid >> 6, lane = tid & 63;
    const int lr = lane & 15, lg = lane >> 4;

    f32x4 acc[2][3];
    #pragma unroll
    for (int i = 0; i < 2; ++i)
        #pragma unroll
        for (int j = 0; j < 3; ++j) acc[i][j] = (f32x4){0.f, 0.f, 0.f, 0.f};

    for (int kc = 0; kc < NN_HF; kc += 64) {
        #pragma unroll
        for (int i = 0; i < 4; ++i) {
            int gi = tid + i * 256;
            int r = gi >> 3;
            int k8 = (gi & 7) << 3;
            bf16x8 v = (bf16x8){0,0,0,0,0,0,0,0};
            if (m0 + r < M)
                v = *(const bf16x8*)(Ab + (size_t)(m0 + r) * NN_HF + kc + k8);
            *reinterpret_cast<bf16x8*>(&Ah[r][k8]) = v;
        }
        #pragma unroll
        for (int i = 0; i < 2; ++i) {
            int gi = tid + i * 256;
            if (gi < 384) {
                int r = gi >> 3;
                int k8 = (gi & 7) << 3;
                *reinterpret_cast<bf16x8*>(&Bh[r][k8]) =
                    *(const bf16x8*)(W2T + (size_t)r * NN_HF + kc + k8);
            }
        }
        __syncthreads();
        #pragma unroll
        for (int ks = 0; ks < 2; ++ks) {
            const int kb = (ks << 5) + (lg << 3);
            bf16x8 fa[2], fb[3];
            #pragma unroll
            for (int mi = 0; mi < 2; ++mi) {
                int r = (wave << 5) + (mi << 4) + lr;
                fa[mi] = *reinterpret_cast<const bf16x8*>(&Ah[r][kb]);
            }
            #pragma unroll
            for (int ni = 0; ni < 3; ++ni) {
                int c = (ni << 4) + lr;
                fb[ni] = *reinterpret_cast<const bf16x8*>(&Bh[c][kb]);
            }
            #pragma unroll
            for (int mi = 0; mi < 2; ++mi)
                #pragma unroll
                for (int ni = 0; ni < 3; ++ni)
                    acc[mi][ni] = __builtin_amdgcn_mfma_f32_16x16x32_bf16(
                        fa[mi], fb[ni], acc[mi][ni], 0, 0, 0);
        }
        __syncthreads();
    }

    float asv[3], adv[3];
    #pragma unroll
    for (int ni = 0; ni < 3; ++ni) {
        int c = (ni << 4) + lr;
        asv[ni] = (c < NN_C) ? att_s[c] : 0.f;
        adv[ni] = (c < NN_C) ? att_d[c] : 0.f;
    }
    #pragma unroll
    for (int mi = 0; mi < 2; ++mi) {
        float ps[4] = {0.f,0.f,0.f,0.f}, pd[4] = {0.f,0.f,0.f,0.f};
        #pragma unroll
        for (int ni = 0; ni < 3; ++ni) {
            int c = (ni << 4) + lr;
            #pragma unroll
            for (int r = 0; r < 4; ++r) {
                float v = acc[mi][ni][r];
                ps[r] = fmaf(v, asv[ni], ps[r]);
                pd[r] = fmaf(v, adv[ni], pd[r]);
                int row = m0 + (wave << 5) + (mi << 4) + (lg << 2) + r;
                if (c < NN_C && row < M)
                    h2b[(size_t)row * NN_C + c] = f2bf_rne(v);
            }
        }
        #pragma unroll
        for (int off = 1; off < 16; off <<= 1) {
            #pragma unroll
            for (int r = 0; r < 4; ++r) {
                ps[r] += __shfl_xor(ps[r], off);
                pd[r] += __shfl_xor(pd[r], off);
            }
        }
        if (lr == 0) {
            #pragma unroll
            for (int r = 0; r < 4; ++r) {
                int row = m0 + (wave << 5) + (mi << 4) + (lg << 2) + r;
                if (row < M) { a2s[row] = ps[r]; a2d[row] = pd[r]; }
            }
        }
    }
}

// ---------------- layer-2 FUSED softmax+aggregate (max-free) + log_softmax ----
__global__ __launch_bounds__(256) void agg2_kernel(
    const unsigned short* __restrict__ h2b, const float* __restrict__ a2s,
    const float* __restrict__ a2d, const int* __restrict__ offs,
    const int* __restrict__ srcs, const float* __restrict__ b2,
    float* __restrict__ out, int Nn)
{
    int n = blockIdx.x * 4 + (threadIdx.x >> 6);
    if (n >= Nn) return;
    int f = threadIdx.x & 63;
    int beg = offs[n], end = offs[n + 1];
    float adn = a2d[n];

    // ---- pass 1: max-free exp-sum ----
    float s = 0.f;
    for (int k = beg + f; k < end; k += 64) {
        float e = a2s[srcs[k]] + adn;
        e = e > 0.f ? e : 0.2f * e;
        s += __expf(e);
    }
    #pragma unroll
    for (int off = 1; off < 64; off <<= 1) s += __shfl_xor(s, off);
    float inv = 1.f / (s + 1e-16f);

    // ---- pass 2: weighted gather + bias + log_softmax ----
    float a0 = 0.f, a1 = 0.f, a2 = 0.f, a3 = 0.f;
    int k = beg;
    for (; k + 3 < end; k += 4) {
        int s0 = srcs[k], s1 = srcs[k+1], s2 = srcs[k+2], s3 = srcs[k+3];
        float e0 = a2s[s0] + adn, e1 = a2s[s1] + adn;
        float e2 = a2s[s2] + adn, e3 = a2s[s3] + adn;
        e0 = e0 > 0.f ? e0 : 0.2f * e0;  e1 = e1 > 0.f ? e1 : 0.2f * e1;
        e2 = e2 > 0.f ? e2 : 0.2f * e2;  e3 = e3 > 0.f ? e3 : 0.2f * e3;
        float w0 = __expf(e0) * inv, w1 = __expf(e1) * inv;
        float w2 = __expf(e2) * inv, w3 = __expf(e3) * inv;
        float h0 = (f < NN_C) ? bfu2f(h2b[(size_t)s0 * NN_C + f]) : 0.f;
        float h1 = (f < NN_C) ? bfu2f(h2b[(size_t)s1 * NN_C + f]) : 0.f;
        float h2v = (f < NN_C) ? bfu2f(h2b[(size_t)s2 * NN_C + f]) : 0.f;
        float h3 = (f < NN_C) ? bfu2f(h2b[(size_t)s3 * NN_C + f]) : 0.f;
        a0 = fmaf(w0, h0, a0); a1 = fmaf(w1, h1, a1);
        a2 = fmaf(w2, h2v, a2); a3 = fmaf(w3, h3, a3);
    }
    for (; k < end; ++k) {
        int s0 = srcs[k];
        float e0 = a2s[s0] + adn;
        e0 = e0 > 0.f ? e0 : 0.2f * e0;
        float w0 = __expf(e0) * inv;
        float h0 = (f < NN_C) ? bfu2f(h2b[(size_t)s0 * NN_C + f]) : 0.f;
        a0 = fmaf(w0, h0, a0);
    }
    float acc = (a0 + a1) + (a2 + a3);
    float v = acc + ((f < NN_C) ? b2[f] : 0.f);
    float lg = (f < NN_C) ? v : -INFINITY;
    float mx = lg;
    #pragma unroll
    for (int off = 32; off >= 1; off >>= 1) mx = fmaxf(mx, __shfl_xor(mx, off));
    float w2e = (f < NN_C) ? __expf(lg - mx) : 0.f;
    float sum = w2e;
    #pragma unroll
    for (int off = 32; off >= 1; off >>= 1) sum += __shfl_xor(sum, off);
    if (f < NN_C) out[(size_t)n * NN_C + f] = lg - mx - __logf(sum);
}

// ---------------- launcher ----------------
extern "C" void kernel_launch(void* const* d_in, const int* in_sizes, int n_in,
                              void* d_out, int out_size, void* d_ws, size_t ws_size,
                              hipStream_t stream)
{
    const float* x    = (const float*)d_in[0];
    const int*   ei   = (const int*)d_in[1];
    const float* W1   = (const float*)d_in[2];
    const float* as1  = (const float*)d_in[3];
    const float* ad1  = (const float*)d_in[4];
    const float* b1   = (const float*)d_in[5];
    const float* W2   = (const float*)d_in[6];
    const float* as2  = (const float*)d_in[7];
    const float* ad2  = (const float*)d_in[8];
    const float* b2   = (const float*)d_in[9];
    float* out = (float*)d_out;

    int Nn = in_sizes[0] / NN_DIN;      // 50000
    int E  = in_sizes[1] / 2;           // 800000
    int Et = E + Nn;
    const int* srcIdx = ei;
    const int* dstIdx = ei + E;

    char* ws = (char*)d_ws;
    size_t off = 0;
    auto alloc = [&](size_t bytes) {
        void* p = ws + off;
        off = (off + bytes + 255) & ~(size_t)255;
        return p;
    };
    unsigned short* h1b  = (unsigned short*)alloc((size_t)Nn * NN_HF * 2);
    unsigned short* W1T  = (unsigned short*)alloc((size_t)NN_HF * NN_DIN * 2);
    unsigned short* W2T  = (unsigned short*)alloc((size_t)48 * NN_HF * 2);
    unsigned short* hp1b = (unsigned short*)alloc((size_t)Nn * NN_HF * 2);
    unsigned short* h2b  = (unsigned short*)alloc((size_t)Nn * NN_C * 2);
    float* a1s  = (float*)alloc((size_t)Nn * NN_H * 4);
    float* a1d  = (float*)alloc((size_t)Nn * NN_H * 4);
    float* a2s  = (float*)alloc((size_t)Nn * 4);
    float* a2d  = (float*)alloc((size_t)Nn * 4);
    int*   deg  = (int*)alloc((size_t)Nn * 4);
    int*   offs = (int*)alloc((size_t)(Nn + 1) * 4);
    int*   bsums= (int*)alloc(1024 * 4);
    int*   curs = (int*)alloc((size_t)Nn * 4);
    int*   srcs = (int*)alloc((size_t)Et * 4);

    hipMemsetAsync(deg, 0, (size_t)Nn * 4, stream);
    hipMemsetAsync(curs, 0, (size_t)Nn * 4, stream);

    // weight prep
    w1rne_kernel<<<dim3(NN_DIN / 32, NN_HF / 32), 256, 0, stream>>>(W1, W1T);
    w2rne_kernel<<<48, 256, 0, stream>>>(W2, W2T);

    // GEMM1 (MFMA, x read once, fused a1s/a1d) -> h1b
    gemm1_kernel<<<(Nn + G1_BM - 1) / G1_BM, 256, 0, stream>>>(
        x, W1T, as1, ad1, h1b, a1s, a1d, Nn);

    // CSR build
    count_kernel<<<(Et + 255) / 256, 256, 0, stream>>>(dstIdx, deg, E, Nn);
    int nb = (Nn + SCAN_CHUNK - 1) / SCAN_CHUNK;
    scan1_kernel<<<nb, 256, 0, stream>>>(deg, offs, bsums, Nn);
    scan2_kernel<<<1, 64, 0, stream>>>(bsums, nb);
    scan3_kernel<<<(Nn + 255) / 256, 256, 0, stream>>>(offs, bsums, Nn, Et);
    fill_kernel<<<(Et + 255) / 256, 256, 0, stream>>>(srcIdx, dstIdx, offs, curs, srcs, E, Nn);

    // layer-1 fused softmax + aggregate (+bias+ELU) -> bf16
    agg1_kernel<<<(Nn + 3) / 4, 256, 0, stream>>>(h1b, a1s, a1d, offs, srcs, b1, hp1b, Nn);

    // GEMM2 (MFMA, fused a2s/a2d) -> bf16 h2
    gemm2_kernel<<<(Nn + G2_BM - 1) / G2_BM, 256, 0, stream>>>(
        hp1b, W2T, as2, ad2, h2b, a2s, a2d, Nn);

    // layer-2 fused softmax + aggregate + bias + log_softmax
    agg2_kernel<<<(Nn + 3) / 4, 256, 0, stream>>>(h2b, a2s, a2d, offs, srcs, b2, out, Nn);
}

// Round 12
// 443.061 us; speedup vs baseline: 1.0014x; 1.0014x over previous
//
#include <hip/hip_runtime.h>
#include <hip/hip_bf16.h>
#include <math.h>

#define NN_DIN 512
#define NN_HF  256
#define NN_H   8
#define NN_F   32
#define NN_C   40

typedef short bf16x8 __attribute__((ext_vector_type(8)));
typedef float f32x4 __attribute__((ext_vector_type(4)));

__device__ __forceinline__ unsigned short f2bf_rne(float x) {
    unsigned u = __builtin_bit_cast(unsigned, x);
    unsigned r = u + 0x7FFFu + ((u >> 16) & 1u);
    return (unsigned short)(r >> 16);
}
__device__ __forceinline__ float bfu2f(unsigned short s) {
    unsigned u = ((unsigned)s) << 16;
    return __builtin_bit_cast(float, u);
}

// ---------------- W1 transpose + RNE bf16: [512][256] f32 -> [256][512] bf16 ----
__global__ __launch_bounds__(256) void w1rne_kernel(
    const float* __restrict__ W1, unsigned short* __restrict__ Wh)
{
    __shared__ float tile[32][33];
    int bk = blockIdx.x * 32;
    int bn = blockIdx.y * 32;
    int tx = threadIdx.x & 31, ty = threadIdx.x >> 5;   // ty 0..7
    #pragma unroll
    for (int i = 0; i < 32; i += 8)
        tile[ty + i][tx] = W1[(size_t)(bk + ty + i) * NN_HF + bn + tx];
    __syncthreads();
    #pragma unroll
    for (int i = 0; i < 32; i += 8) {
        float v = tile[tx][ty + i];
        Wh[(size_t)(bn + ty + i) * NN_DIN + bk + tx] = f2bf_rne(v);
    }
}

// ---------------- W2 transpose + RNE bf16: [256][40] f32 -> [48][256] bf16 (pad 0) ----
__global__ __launch_bounds__(256) void w2rne_kernel(
    const float* __restrict__ W2, unsigned short* __restrict__ W2T)
{
    int idx = blockIdx.x * 256 + threadIdx.x;    // 48*256 = 12288
    if (idx >= 48 * 256) return;
    int c = idx >> 8;       // output col (row of W2T), 0..47
    int k = idx & 255;
    unsigned short v = 0;
    if (c < NN_C) v = f2bf_rne(W2[(size_t)k * NN_C + c]);
    W2T[idx] = v;
}

// ---------------- GEMM1 (MFMA, x read once) + fused a1s/a1d epilogue ----------
#define G1_BM 64
#define G1_BN 256
#define G1_BK 64
#define G1_LDK 72

__global__ __launch_bounds__(256) void gemm1_kernel(
    const float* __restrict__ A, const unsigned short* __restrict__ BT,
    const float* __restrict__ as1, const float* __restrict__ ad1,
    unsigned short* __restrict__ Cb, float* __restrict__ a1s,
    float* __restrict__ a1d, int M)
{
    __shared__ unsigned short Ah[G1_BM][G1_LDK];
    __shared__ unsigned short Bh[G1_BN][G1_LDK];
    const int m0 = blockIdx.x * G1_BM;
    const int tid = threadIdx.x;
    const int wave = tid >> 6, lane = tid & 63;
    const int wn = wave;
    const int lr = lane & 15, lg = lane >> 4;

    const int amr[4] = { (tid + 0*256) >> 4, (tid + 1*256) >> 4,
                         (tid + 2*256) >> 4, (tid + 3*256) >> 4 };
    const int akc = (tid & 15) << 2;
    const int bnr[8] = { (tid + 0*256) >> 3, (tid + 1*256) >> 3,
                         (tid + 2*256) >> 3, (tid + 3*256) >> 3,
                         (tid + 4*256) >> 3, (tid + 5*256) >> 3,
                         (tid + 6*256) >> 3, (tid + 7*256) >> 3 };
    const int bkc = (tid & 7) << 3;

    f32x4 acc[4][4];
    #pragma unroll
    for (int i = 0; i < 4; ++i)
        #pragma unroll
        for (int j = 0; j < 4; ++j) acc[i][j] = (f32x4){0.f, 0.f, 0.f, 0.f};

    float4 ra[4];
    bf16x8 rb[8];

    #pragma unroll
    for (int i = 0; i < 4; ++i) {
        ra[i] = make_float4(0.f, 0.f, 0.f, 0.f);
        if (m0 + amr[i] < M)
            ra[i] = *(const float4*)(A + (size_t)(m0 + amr[i]) * NN_DIN + akc);
    }
    #pragma unroll
    for (int i = 0; i < 8; ++i)
        rb[i] = *(const bf16x8*)(BT + (size_t)bnr[i] * NN_DIN + bkc);
    #pragma unroll
    for (int i = 0; i < 4; ++i) {
        ushort4 hv;
        hv.x = f2bf_rne(ra[i].x); hv.y = f2bf_rne(ra[i].y);
        hv.z = f2bf_rne(ra[i].z); hv.w = f2bf_rne(ra[i].w);
        *reinterpret_cast<ushort4*>(&Ah[amr[i]][akc]) = hv;
    }
    #pragma unroll
    for (int i = 0; i < 8; ++i)
        *reinterpret_cast<bf16x8*>(&Bh[bnr[i]][bkc]) = rb[i];
    __syncthreads();

    const int NSTEP = NN_DIN / G1_BK;   // 8
    for (int step = 0; step < NSTEP; ++step) {
        const bool last = (step == NSTEP - 1);
        if (!last) {
            int k0 = (step + 1) * G1_BK;
            #pragma unroll
            for (int i = 0; i < 4; ++i) {
                ra[i] = make_float4(0.f, 0.f, 0.f, 0.f);
                if (m0 + amr[i] < M)
                    ra[i] = *(const float4*)(A + (size_t)(m0 + amr[i]) * NN_DIN + k0 + akc);
            }
            #pragma unroll
            for (int i = 0; i < 8; ++i)
                rb[i] = *(const bf16x8*)(BT + (size_t)bnr[i] * NN_DIN + k0 + bkc);
        }
        #pragma unroll
        for (int ks = 0; ks < 2; ++ks) {
            const int kb = (ks << 5) + (lg << 3);
            bf16x8 fah[4], fbh[4];
            #pragma unroll
            for (int mi = 0; mi < 4; ++mi) {
                int m = (mi << 4) + lr;
                fah[mi] = *reinterpret_cast<const bf16x8*>(&Ah[m][kb]);
            }
            #pragma unroll
            for (int ni = 0; ni < 4; ++ni) {
                int n = (wn << 6) + (ni << 4) + lr;
                fbh[ni] = *reinterpret_cast<const bf16x8*>(&Bh[n][kb]);
            }
            #pragma unroll
            for (int mi = 0; mi < 4; ++mi)
                #pragma unroll
                for (int ni = 0; ni < 4; ++ni)
                    acc[mi][ni] = __builtin_amdgcn_mfma_f32_16x16x32_bf16(
                        fah[mi], fbh[ni], acc[mi][ni], 0, 0, 0);
        }
        __syncthreads();
        if (!last) {
            #pragma unroll
            for (int i = 0; i < 4; ++i) {
                ushort4 hv;
                hv.x = f2bf_rne(ra[i].x); hv.y = f2bf_rne(ra[i].y);
                hv.z = f2bf_rne(ra[i].z); hv.w = f2bf_rne(ra[i].w);
                *reinterpret_cast<ushort4*>(&Ah[amr[i]][akc]) = hv;
            }
            #pragma unroll
            for (int i = 0; i < 8; ++i)
                *reinterpret_cast<bf16x8*>(&Bh[bnr[i]][bkc]) = rb[i];
            __syncthreads();
        }
    }
    // epilogue: C write + fused attention-coefficient reduction.
    float asv[4], adv[4];
    #pragma unroll
    for (int ni = 0; ni < 4; ++ni) {
        int c = (wn << 6) + (ni << 4) + lr;
        asv[ni] = as1[c]; adv[ni] = ad1[c];
    }
    #pragma unroll
    for (int mi = 0; mi < 4; ++mi)
        #pragma unroll
        for (int r = 0; r < 4; ++r) {
            int row = m0 + (mi << 4) + (lg << 2) + r;
            float v0 = acc[mi][0][r], v1 = acc[mi][1][r];
            float v2 = acc[mi][2][r], v3 = acc[mi][3][r];
            if (row < M) {
                Cb[(size_t)row * NN_HF + (wn << 6) + (0 << 4) + lr] = f2bf_rne(v0);
                Cb[(size_t)row * NN_HF + (wn << 6) + (1 << 4) + lr] = f2bf_rne(v1);
                Cb[(size_t)row * NN_HF + (wn << 6) + (2 << 4) + lr] = f2bf_rne(v2);
                Cb[(size_t)row * NN_HF + (wn << 6) + (3 << 4) + lr] = f2bf_rne(v3);
            }
            float ps0 = v0 * asv[0] + v1 * asv[1];
            float pd0 = v0 * adv[0] + v1 * adv[1];
            float ps1 = v2 * asv[2] + v3 * asv[3];
            float pd1 = v2 * adv[2] + v3 * adv[3];
            #pragma unroll
            for (int off = 1; off < 16; off <<= 1) {
                ps0 += __shfl_xor(ps0, off); pd0 += __shfl_xor(pd0, off);
                ps1 += __shfl_xor(ps1, off); pd1 += __shfl_xor(pd1, off);
            }
            if (lr == 0 && row < M) {
                a1s[row * NN_H + 2 * wn]     = ps0;
                a1s[row * NN_H + 2 * wn + 1] = ps1;
                a1d[row * NN_H + 2 * wn]     = pd0;
                a1d[row * NN_H + 2 * wn + 1] = pd1;
            }
        }
}

// ---------------- CSR build ----------------
__global__ void count_kernel(const int* __restrict__ dst, int* __restrict__ deg,
                             int E, int Nn)
{
    int e = blockIdx.x * blockDim.x + threadIdx.x;
    int Et = E + Nn;
    if (e >= Et) return;
    int d = (e < E) ? dst[e] : (e - E);     // self-loops appended
    atomicAdd(&deg[d], 1);
}

#define SCAN_CHUNK 1024
__global__ __launch_bounds__(256) void scan1_kernel(
    const int* __restrict__ deg, int* __restrict__ offs,
    int* __restrict__ bsums, int Nn)
{
    __shared__ int sh[256];
    int b = blockIdx.x, t = threadIdx.x;
    int base = b * SCAN_CHUNK + t * 4;
    int v[4];
    int tot = 0;
    #pragma unroll
    for (int i = 0; i < 4; ++i) {
        v[i] = (base + i < Nn) ? deg[base + i] : 0;
        tot += v[i];
    }
    sh[t] = tot;
    __syncthreads();
    for (int off = 1; off < 256; off <<= 1) {
        int y = (t >= off) ? sh[t - off] : 0;
        __syncthreads();
        sh[t] += y;
        __syncthreads();
    }
    int p = sh[t] - tot;
    #pragma unroll
    for (int i = 0; i < 4; ++i) {
        if (base + i < Nn) offs[base + i] = p;
        p += v[i];
    }
    if (t == 255) bsums[b] = sh[255];
}

__global__ void scan2_kernel(int* __restrict__ bsums, int nb)
{
    if (threadIdx.x == 0) {
        int run = 0;
        for (int i = 0; i < nb; ++i) {
            int tmp = bsums[i];
            bsums[i] = run;
            run += tmp;
        }
    }
}

__global__ void scan3_kernel(int* __restrict__ offs, const int* __restrict__ bsums,
                             int Nn, int Et)
{
    int i = blockIdx.x * blockDim.x + threadIdx.x;
    if (i < Nn) offs[i] += bsums[i >> 10];
    if (i == 0) offs[Nn] = Et;
}

__global__ void fill_kernel(const int* __restrict__ src, const int* __restrict__ dst,
                            const int* __restrict__ offs, int* __restrict__ cursor,
                            int* __restrict__ srcs, int E, int Nn)
{
    int e = blockIdx.x * blockDim.x + threadIdx.x;
    int Et = E + Nn;
    if (e >= Et) return;
    int d, s;
    if (e < E) { d = dst[e]; s = src[e]; }
    else       { d = e - E;  s = e - E;  }
    int pos = offs[d] + atomicAdd(&cursor[d], 1);
    srcs[pos] = s;
}

// ---------------- layer-1 FUSED softmax+aggregate (max-free) -> bf16 ---------
// pass 1: s=sum(exp) per head (8 groups x 8 heads). pass 2: half-wave per edge,
// lane covers 8 features (bf16x8 load = 2 rows per wave instruction).
__global__ __launch_bounds__(256) void agg1_kernel(
    const unsigned short* __restrict__ h1b, const float* __restrict__ a1s,
    const float* __restrict__ a1d, const int* __restrict__ offs,
    const int* __restrict__ srcs, const float* __restrict__ b1,
    unsigned short* __restrict__ hp1b, int Nn)
{
    int n = blockIdx.x * 4 + (threadIdx.x >> 6);
    if (n >= Nn) return;
    int lane = threadIdx.x & 63;
    int beg = offs[n], end = offs[n + 1];

    // ---- pass 1: max-free exp-sum per head ----
    int g = lane >> 3, hh = lane & 7;
    float adn1 = a1d[n * NN_H + hh];
    float s = 0.f;
    for (int k = beg + g; k < end; k += 8) {
        float e = a1s[srcs[k] * NN_H + hh] + adn1;
        e = e > 0.f ? e : 0.2f * e;
        s += __expf(e);
    }
    #pragma unroll
    for (int off = 8; off < 64; off <<= 1) s += __shfl_xor(s, off);
    float inv = 1.f / (s + 1e-16f);

    // ---- pass 2 layout ----
    int hl = lane & 31;          // position in half-wave; features 8*hl..8*hl+7
    int h = hl >> 2;             // head (4 lanes x 8 feats = 32 feats)
    int half = lane >> 5;        // which edge of the pair
    float invh = __shfl(inv, h);     // lane h holds head h's sum (g=0 slot)
    float adn  = __shfl(adn1, h);

    float c0[8] = {0,0,0,0,0,0,0,0};
    float c1[8] = {0,0,0,0,0,0,0,0};
    int k = beg;
    for (; k + 3 < end; k += 4) {
        int s0 = srcs[k + half];
        int s1 = srcs[k + 2 + half];
        float e0 = a1s[s0 * NN_H + h] + adn;
        float e1 = a1s[s1 * NN_H + h] + adn;
        e0 = e0 > 0.f ? e0 : 0.2f * e0;
        e1 = e1 > 0.f ? e1 : 0.2f * e1;
        float w0 = __expf(e0) * invh;
        float w1 = __expf(e1) * invh;
        bf16x8 v0 = *(const bf16x8*)(h1b + (size_t)s0 * NN_HF + hl * 8);
        bf16x8 v1 = *(const bf16x8*)(h1b + (size_t)s1 * NN_HF + hl * 8);
        #pragma unroll
        for (int j = 0; j < 8; ++j) {
            c0[j] = fmaf(w0, bfu2f((unsigned short)v0[j]), c0[j]);
            c1[j] = fmaf(w1, bfu2f((unsigned short)v1[j]), c1[j]);
        }
    }
    for (; k + 1 < end; k += 2) {
        int s0 = srcs[k + half];
        float e0 = a1s[s0 * NN_H + h] + adn;
        e0 = e0 > 0.f ? e0 : 0.2f * e0;
        float w0 = __expf(e0) * invh;
        bf16x8 v0 = *(const bf16x8*)(h1b + (size_t)s0 * NN_HF + hl * 8);
        #pragma unroll
        for (int j = 0; j < 8; ++j)
            c0[j] = fmaf(w0, bfu2f((unsigned short)v0[j]), c0[j]);
    }
    if (k < end) {
        int s0 = srcs[k];
        float e0 = a1s[s0 * NN_H + h] + adn;
        e0 = e0 > 0.f ? e0 : 0.2f * e0;
        float w0 = (half == 0) ? __expf(e0) * invh : 0.f;
        bf16x8 v0 = *(const bf16x8*)(h1b + (size_t)s0 * NN_HF + hl * 8);
        #pragma unroll
        for (int j = 0; j < 8; ++j)
            c0[j] = fmaf(w0, bfu2f((unsigned short)v0[j]), c0[j]);
    }
    // combine pair accumulators + cross-half reduce
    #pragma unroll
    for (int j = 0; j < 8; ++j) {
        c0[j] += c1[j];
        c0[j] += __shfl_xor(c0[j], 32);
    }
    if (half == 0) {
        float4 bb0 = *(const float4*)(b1 + hl * 8);
        float4 bb1 = *(const float4*)(b1 + hl * 8 + 4);
        float r[8];
        r[0] = c0[0] + bb0.x; r[1] = c0[1] + bb0.y;
        r[2] = c0[2] + bb0.z; r[3] = c0[3] + bb0.w;
        r[4] = c0[4] + bb1.x; r[5] = c0[5] + bb1.y;
        r[6] = c0[6] + bb1.z; r[7] = c0[7] + bb1.w;
        bf16x8 ov;
        #pragma unroll
        for (int j = 0; j < 8; ++j) {
            float v = r[j] > 0.f ? r[j] : __expf(r[j]) - 1.f;   // ELU
            ov[j] = (short)f2bf_rne(v);
        }
        *(bf16x8*)(hp1b + (size_t)n * NN_HF + hl * 8) = ov;
    }
}

// ---------------- GEMM2 (MFMA): h2b = bf16(hp1b @ W2), fused a2s/a2d ----------
#define G2_BM 128

__global__ __launch_bounds__(256) void gemm2_kernel(
    const unsigned short* __restrict__ Ab, const unsigned short* __restrict__ W2T,
    const float* __restrict__ att_s, const float* __restrict__ att_d,
    unsigned short* __restrict__ h2b, float* __restrict__ a2s,
    float* __restrict__ a2d, int M)
{
    __shared__ unsigned short Ah[G2_BM][72];
    __shared__ unsigned short Bh[48][72];
    const int m0 = blockIdx.x * G2_BM;
    const int tid = threadIdx.x;
    const int wave = tid >> 6, lane = tid & 63;
    const int lr = lane & 15, lg = lane >> 4;

    f32x4 acc[2][3];
    #pragma unroll
    for (int i = 0; i < 2; ++i)
        #pragma unroll
        for (int j = 0; j < 3; ++j) acc[i][j] = (f32x4){0.f, 0.f, 0.f, 0.f};

    for (int kc = 0; kc < NN_HF; kc += 64) {
        #pragma unroll
        for (int i = 0; i < 4; ++i) {
            int gi = tid + i * 256;
            int r = gi >> 3;
            int k8 = (gi & 7) << 3;
            bf16x8 v = (bf16x8){0,0,0,0,0,0,0,0};
            if (m0 + r < M)
                v = *(const bf16x8*)(Ab + (size_t)(m0 + r) * NN_HF + kc + k8);
            *reinterpret_cast<bf16x8*>(&Ah[r][k8]) = v;
        }
        #pragma unroll
        for (int i = 0; i < 2; ++i) {
            int gi = tid + i * 256;
            if (gi < 384) {
                int r = gi >> 3;
                int k8 = (gi & 7) << 3;
                *reinterpret_cast<bf16x8*>(&Bh[r][k8]) =
                    *(const bf16x8*)(W2T + (size_t)r * NN_HF + kc + k8);
            }
        }
        __syncthreads();
        #pragma unroll
        for (int ks = 0; ks < 2; ++ks) {
            const int kb = (ks << 5) + (lg << 3);
            bf16x8 fa[2], fb[3];
            #pragma unroll
            for (int mi = 0; mi < 2; ++mi) {
                int r = (wave << 5) + (mi << 4) + lr;
                fa[mi] = *reinterpret_cast<const bf16x8*>(&Ah[r][kb]);
            }
            #pragma unroll
            for (int ni = 0; ni < 3; ++ni) {
                int c = (ni << 4) + lr;
                fb[ni] = *reinterpret_cast<const bf16x8*>(&Bh[c][kb]);
            }
            #pragma unroll
            for (int mi = 0; mi < 2; ++mi)
                #pragma unroll
                for (int ni = 0; ni < 3; ++ni)
                    acc[mi][ni] = __builtin_amdgcn_mfma_f32_16x16x32_bf16(
                        fa[mi], fb[ni], acc[mi][ni], 0, 0, 0);
        }
        __syncthreads();
    }

    float asv[3], adv[3];
    #pragma unroll
    for (int ni = 0; ni < 3; ++ni) {
        int c = (ni << 4) + lr;
        asv[ni] = (c < NN_C) ? att_s[c] : 0.f;
        adv[ni] = (c < NN_C) ? att_d[c] : 0.f;
    }
    #pragma unroll
    for (int mi = 0; mi < 2; ++mi) {
        float ps[4] = {0.f,0.f,0.f,0.f}, pd[4] = {0.f,0.f,0.f,0.f};
        #pragma unroll
        for (int ni = 0; ni < 3; ++ni) {
            int c = (ni << 4) + lr;
            #pragma unroll
            for (int r = 0; r < 4; ++r) {
                float v = acc[mi][ni][r];
                ps[r] = fmaf(v, asv[ni], ps[r]);
                pd[r] = fmaf(v, adv[ni], pd[r]);
                int row = m0 + (wave << 5) + (mi << 4) + (lg << 2) + r;
                if (c < NN_C && row < M)
                    h2b[(size_t)row * NN_C + c] = f2bf_rne(v);
            }
        }
        #pragma unroll
        for (int off = 1; off < 16; off <<= 1) {
            #pragma unroll
            for (int r = 0; r < 4; ++r) {
                ps[r] += __shfl_xor(ps[r], off);
                pd[r] += __shfl_xor(pd[r], off);
            }
        }
        if (lr == 0) {
            #pragma unroll
            for (int r = 0; r < 4; ++r) {
                int row = m0 + (wave << 5) + (mi << 4) + (lg << 2) + r;
                if (row < M) { a2s[row] = ps[r]; a2d[row] = pd[r]; }
            }
        }
    }
}

// ---------------- layer-2 FUSED softmax+aggregate (max-free) + log_softmax ----
__global__ __launch_bounds__(256) void agg2_kernel(
    const unsigned short* __restrict__ h2b, const float* __restrict__ a2s,
    const float* __restrict__ a2d, const int* __restrict__ offs,
    const int* __restrict__ srcs, const float* __restrict__ b2,
    float* __restrict__ out, int Nn)
{
    int n = blockIdx.x * 4 + (threadIdx.x >> 6);
    if (n >= Nn) return;
    int f = threadIdx.x & 63;
    int beg = offs[n], end = offs[n + 1];
    float adn = a2d[n];

    // ---- pass 1: max-free exp-sum ----
    float s = 0.f;
    for (int k = beg + f; k < end; k += 64) {
        float e = a2s[srcs[k]] + adn;
        e = e > 0.f ? e : 0.2f * e;
        s += __expf(e);
    }
    #pragma unroll
    for (int off = 1; off < 64; off <<= 1) s += __shfl_xor(s, off);
    float inv = 1.f / (s + 1e-16f);

    // ---- pass 2: weighted gather + bias + log_softmax ----
    float a0 = 0.f, a1 = 0.f, a2 = 0.f, a3 = 0.f;
    int k = beg;
    for (; k + 3 < end; k += 4) {
        int s0 = srcs[k], s1 = srcs[k+1], s2 = srcs[k+2], s3 = srcs[k+3];
        float e0 = a2s[s0] + adn, e1 = a2s[s1] + adn;
        float e2 = a2s[s2] + adn, e3 = a2s[s3] + adn;
        e0 = e0 > 0.f ? e0 : 0.2f * e0;  e1 = e1 > 0.f ? e1 : 0.2f * e1;
        e2 = e2 > 0.f ? e2 : 0.2f * e2;  e3 = e3 > 0.f ? e3 : 0.2f * e3;
        float w0 = __expf(e0) * inv, w1 = __expf(e1) * inv;
        float w2 = __expf(e2) * inv, w3 = __expf(e3) * inv;
        float h0 = (f < NN_C) ? bfu2f(h2b[(size_t)s0 * NN_C + f]) : 0.f;
        float h1 = (f < NN_C) ? bfu2f(h2b[(size_t)s1 * NN_C + f]) : 0.f;
        float h2v = (f < NN_C) ? bfu2f(h2b[(size_t)s2 * NN_C + f]) : 0.f;
        float h3 = (f < NN_C) ? bfu2f(h2b[(size_t)s3 * NN_C + f]) : 0.f;
        a0 = fmaf(w0, h0, a0); a1 = fmaf(w1, h1, a1);
        a2 = fmaf(w2, h2v, a2); a3 = fmaf(w3, h3, a3);
    }
    for (; k < end; ++k) {
        int s0 = srcs[k];
        float e0 = a2s[s0] + adn;
        e0 = e0 > 0.f ? e0 : 0.2f * e0;
        float w0 = __expf(e0) * inv;
        float h0 = (f < NN_C) ? bfu2f(h2b[(size_t)s0 * NN_C + f]) : 0.f;
        a0 = fmaf(w0, h0, a0);
    }
    float acc = (a0 + a1) + (a2 + a3);
    float v = acc + ((f < NN_C) ? b2[f] : 0.f);
    float lg = (f < NN_C) ? v : -INFINITY;
    float mx = lg;
    #pragma unroll
    for (int off = 32; off >= 1; off >>= 1) mx = fmaxf(mx, __shfl_xor(mx, off));
    float w2e = (f < NN_C) ? __expf(lg - mx) : 0.f;
    float sum = w2e;
    #pragma unroll
    for (int off = 32; off >= 1; off >>= 1) sum += __shfl_xor(sum, off);
    if (f < NN_C) out[(size_t)n * NN_C + f] = lg - mx - __logf(sum);
}

// ---------------- launcher ----------------
extern "C" void kernel_launch(void* const* d_in, const int* in_sizes, int n_in,
                              void* d_out, int out_size, void* d_ws, size_t ws_size,
                              hipStream_t stream)
{
    const float* x    = (const float*)d_in[0];
    const int*   ei   = (const int*)d_in[1];
    const float* W1   = (const float*)d_in[2];
    const float* as1  = (const float*)d_in[3];
    const float* ad1  = (const float*)d_in[4];
    const float* b1   = (const float*)d_in[5];
    const float* W2   = (const float*)d_in[6];
    const float* as2  = (const float*)d_in[7];
    const float* ad2  = (const float*)d_in[8];
    const float* b2   = (const float*)d_in[9];
    float* out = (float*)d_out;

    int Nn = in_sizes[0] / NN_DIN;      // 50000
    int E  = in_sizes[1] / 2;           // 800000
    int Et = E + Nn;
    const int* srcIdx = ei;
    const int* dstIdx = ei + E;

    char* ws = (char*)d_ws;
    size_t off = 0;
    auto alloc = [&](size_t bytes) {
        void* p = ws + off;
        off = (off + bytes + 255) & ~(size_t)255;
        return p;
    };
    unsigned short* h1b  = (unsigned short*)alloc((size_t)Nn * NN_HF * 2);
    unsigned short* W1T  = (unsigned short*)alloc((size_t)NN_HF * NN_DIN * 2);
    unsigned short* W2T  = (unsigned short*)alloc((size_t)48 * NN_HF * 2);
    unsigned short* hp1b = (unsigned short*)alloc((size_t)Nn * NN_HF * 2);
    unsigned short* h2b  = (unsigned short*)alloc((size_t)Nn * NN_C * 2);
    float* a1s  = (float*)alloc((size_t)Nn * NN_H * 4);
    float* a1d  = (float*)alloc((size_t)Nn * NN_H * 4);
    float* a2s  = (float*)alloc((size_t)Nn * 4);
    float* a2d  = (float*)alloc((size_t)Nn * 4);
    int*   deg  = (int*)alloc((size_t)Nn * 4);
    int*   offs = (int*)alloc((size_t)(Nn + 1) * 4);
    int*   bsums= (int*)alloc(1024 * 4);
    int*   curs = (int*)alloc((size_t)Nn * 4);
    int*   srcs = (int*)alloc((size_t)Et * 4);

    hipMemsetAsync(deg, 0, (size_t)Nn * 4, stream);
    hipMemsetAsync(curs, 0, (size_t)Nn * 4, stream);

    // weight prep
    w1rne_kernel<<<dim3(NN_DIN / 32, NN_HF / 32), 256, 0, stream>>>(W1, W1T);
    w2rne_kernel<<<48, 256, 0, stream>>>(W2, W2T);

    // GEMM1 (MFMA, x read once, fused a1s/a1d) -> h1b
    gemm1_kernel<<<(Nn + G1_BM - 1) / G1_BM, 256, 0, stream>>>(
        x, W1T, as1, ad1, h1b, a1s, a1d, Nn);

    // CSR build
    count_kernel<<<(Et + 255) / 256, 256, 0, stream>>>(dstIdx, deg, E, Nn);
    int nb = (Nn + SCAN_CHUNK - 1) / SCAN_CHUNK;
    scan1_kernel<<<nb, 256, 0, stream>>>(deg, offs, bsums, Nn);
    scan2_kernel<<<1, 64, 0, stream>>>(bsums, nb);
    scan3_kernel<<<(Nn + 255) / 256, 256, 0, stream>>>(offs, bsums, Nn, Et);
    fill_kernel<<<(Et + 255) / 256, 256, 0, stream>>>(srcIdx, dstIdx, offs, curs, srcs, E, Nn);

    // layer-1 fused softmax + aggregate (+bias+ELU) -> bf16
    agg1_kernel<<<(Nn + 3) / 4, 256, 0, stream>>>(h1b, a1s, a1d, offs, srcs, b1, hp1b, Nn);

    // GEMM2 (MFMA, fused a2s/a2d) -> bf16 h2
    gemm2_kernel<<<(Nn + G2_BM - 1) / G2_BM, 256, 0, stream>>>(
        hp1b, W2T, as2, ad2, h2b, a2s, a2d, Nn);

    // layer-2 fused softmax + aggregate + bias + log_softmax
    agg2_kernel<<<(Nn + 3) / 4, 256, 0, stream>>>(h2b, a2s, a2d, offs, srcs, b2, out, Nn);
}